// Round 1
// baseline (1435.439 us; speedup 1.0000x reference)
//
#include <hip/hip_runtime.h>

#define TT 4
#define NN 50000
#define DH 64
#define EE 800000
#define BN_EPS 1e-5f

// ---------------- ws layout (byte offsets) ----------------
// Z/rZ        @ 0        (50000 f = 200000 B)
// sums_x      @ 200192   (256 f)
// sumsq_x     @ 201216   (256 f)
// sum_avg     @ 202240   (64 f)
// sumsq_avg   @ 202496   (64 f)   -> memset [0, 202752)
// W1eff       @ 204800   (12288 f)
// b1eff       @ 253952   (64 f)
// agg         @ 262144   (12.8M f = 51.2 MB) -> memset separately
#define WS_Z        0
#define WS_SUMS_X   200192
#define WS_SUMSQ_X  201216
#define WS_SUM_A    202240
#define WS_SUMSQ_A  202496
#define WS_STATS_END 202752
#define WS_W1EFF    204800
#define WS_B1EFF    253952
#define WS_AGG      262144

__global__ void k_degree(const float* __restrict__ ew, const int* __restrict__ dst,
                         float* __restrict__ Z) {
    int e = blockIdx.x * 256 + threadIdx.x;
    if (e < EE) atomicAdd(&Z[dst[e]], ew[e]);
}

__global__ void k_rz(float* __restrict__ Z) {
    int n = blockIdx.x * 256 + threadIdx.x;
    if (n < NN) {
        float z = Z[n];
        Z[n] = (z == 0.0f) ? 1.0f : (1.0f / z);
    }
}

// one wave per edge: lanes = 64 channels; loop over T
__global__ void k_scatter(const float* __restrict__ x, const float* __restrict__ ew,
                          const int* __restrict__ src, const int* __restrict__ dst,
                          float* __restrict__ agg) {
    int gid = blockIdx.x * 256 + threadIdx.x;   // e*64 + c, total EE*64 exactly
    int c = gid & 63;
    int e = gid >> 6;
    int s = src[e], d = dst[e];
    float w = ew[e];
#pragma unroll
    for (int t = 0; t < TT; ++t) {
        float v = w * x[(size_t)(t * NN + s) * 64 + c];
        atomicAdd(&agg[(size_t)(t * NN + d) * 64 + c], v);
    }
}

// per-(t,c) sum & sumsq of node_data
__global__ void k_stats_x(const float* __restrict__ x, float* __restrict__ sums,
                          float* __restrict__ sumsq) {
    int t = blockIdx.y;
    int g = blockIdx.x * 256 + threadIdx.x;
    int stride = gridDim.x * 256;               // multiple of 64 -> c fixed per thread
    const float* xt = x + (size_t)t * NN * 64;
    float s = 0.f, s2 = 0.f;
    for (int i = g; i < NN * 64; i += stride) {
        float v = xt[i];
        s += v; s2 += v * v;
    }
    __shared__ float ls[256], ls2[256];
    ls[threadIdx.x] = s; ls2[threadIdx.x] = s2;
    __syncthreads();
    if (threadIdx.x < 64) {
        s  = ls[threadIdx.x]  + ls[threadIdx.x + 64]  + ls[threadIdx.x + 128]  + ls[threadIdx.x + 192];
        s2 = ls2[threadIdx.x] + ls2[threadIdx.x + 64] + ls2[threadIdx.x + 128] + ls2[threadIdx.x + 192];
        atomicAdd(&sums[t * 64 + threadIdx.x], s);
        atomicAdd(&sumsq[t * 64 + threadIdx.x], s2);
    }
}

// per-c sum & sumsq of avg = agg * rZ  (accumulated over all t)
__global__ void k_stats_avg(const float* __restrict__ agg, const float* __restrict__ rZ,
                            float* __restrict__ sums, float* __restrict__ sumsq) {
    int t = blockIdx.y;
    int g = blockIdx.x * 256 + threadIdx.x;
    int stride = gridDim.x * 256;
    const float* at = agg + (size_t)t * NN * 64;
    float s = 0.f, s2 = 0.f;
    for (int i = g; i < NN * 64; i += stride) {
        float v = at[i] * rZ[i >> 6];
        s += v; s2 += v * v;
    }
    __shared__ float ls[256], ls2[256];
    ls[threadIdx.x] = s; ls2[threadIdx.x] = s2;
    __syncthreads();
    if (threadIdx.x < 64) {
        s  = ls[threadIdx.x]  + ls[threadIdx.x + 64]  + ls[threadIdx.x + 128]  + ls[threadIdx.x + 192];
        s2 = ls2[threadIdx.x] + ls2[threadIdx.x + 64] + ls2[threadIdx.x + 128] + ls2[threadIdx.x + 192];
        atomicAdd(&sums[threadIdx.x], s);
        atomicAdd(&sumsq[threadIdx.x], s2);
    }
}

// finalize BN stats, fold gamma/beta/mu/rstd into W1eff / b1eff
__global__ void k_fold(const float* __restrict__ W1, const float* __restrict__ b1,
                       const float* __restrict__ gamma, const float* __restrict__ beta,
                       const float* __restrict__ sums_x, const float* __restrict__ sumsq_x,
                       const float* __restrict__ sum_avg, const float* __restrict__ sumsq_avg,
                       float* __restrict__ W1eff, float* __restrict__ b1eff) {
    __shared__ float gS[192], hS[192];
    int c = threadIdx.x;                        // 192 threads
    const float inv = 1.0f / (float)(TT * NN);
    if (c < 192) {
        float mu, ex2;
        if (c < 64) {
            float s = 0.f, s2 = 0.f;
            for (int t = 0; t < TT; ++t) { s += sums_x[t * 64 + c]; s2 += sumsq_x[t * 64 + c]; }
            mu = s * inv; ex2 = s2 * inv;
        } else if (c < 128) {
            int cc = c - 64;
            float s = 0.f, s2 = 0.f;
            for (int t = 0; t < TT - 1; ++t) { s += sums_x[t * 64 + cc]; s2 += sumsq_x[t * 64 + cc]; }
            mu = s * inv; ex2 = s2 * inv;       // t=0 prev row is zeros -> contributes 0
        } else {
            int cc = c - 128;
            mu = sum_avg[cc] * inv; ex2 = sumsq_avg[cc] * inv;
        }
        float var = ex2 - mu * mu;
        float g = gamma[c] / sqrtf(var + BN_EPS);
        gS[c] = g;
        hS[c] = beta[c] - mu * g;
    }
    __syncthreads();
    for (int i = threadIdx.x; i < 64 * 192; i += blockDim.x) {
        int cc = i % 192;
        W1eff[i] = W1[i] * gS[cc];
    }
    if (threadIdx.x < 64) {
        int o = threadIdx.x;
        float acc = b1[o];
        for (int cc = 0; cc < 192; ++cc) acc += hS[cc] * W1[o * 192 + cc];
        b1eff[o] = acc;
    }
}

// main fused GEMM: one thread per row r=(t,n); 64 outputs in registers.
__global__ __launch_bounds__(256) void k_main(
    const float* __restrict__ x, const float* __restrict__ agg,
    const float* __restrict__ rZ, const float* __restrict__ W,
    const float* __restrict__ bias, float* __restrict__ out) {
    int r = blockIdx.x * 256 + threadIdx.x;
    if (r >= TT * NN) return;
    int t = r / NN;
    int n = r - t * NN;
    float acc[64];
#pragma unroll
    for (int o = 0; o < 64; ++o) acc[o] = 0.f;

    const float* xrow = x + (size_t)r * 64;
    const float* prow = x + (size_t)(r - NN) * 64;  // only dereferenced when t>0
    const float* arow = agg + (size_t)r * 64;
    float rz = rZ[n];
    bool has_prev = (t > 0);

#pragma unroll 1
    for (int hc = 0; hc < 12; ++hc) {
        float a[16];
        int c0 = hc * 16;
        if (hc < 4) {
#pragma unroll
            for (int j = 0; j < 16; ++j) a[j] = xrow[c0 + j];
        } else if (hc < 8) {
            if (has_prev) {
#pragma unroll
                for (int j = 0; j < 16; ++j) a[j] = prow[c0 - 64 + j];
            } else {
#pragma unroll
                for (int j = 0; j < 16; ++j) a[j] = 0.f;
            }
        } else {
#pragma unroll
            for (int j = 0; j < 16; ++j) a[j] = arow[c0 - 128 + j] * rz;
        }
        const float* Wc = W + c0;                 // lane-uniform addresses -> s_load
#pragma unroll
        for (int o = 0; o < 64; ++o) {
#pragma unroll
            for (int j = 0; j < 16; ++j) acc[o] = fmaf(a[j], Wc[o * 192 + j], acc[o]);
        }
    }
    float* orow = out + (size_t)r * 64;
#pragma unroll
    for (int o = 0; o < 64; ++o) orow[o] = fmaxf(acc[o] + bias[o], 0.f);
}

extern "C" void kernel_launch(void* const* d_in, const int* in_sizes, int n_in,
                              void* d_out, int out_size, void* d_ws, size_t ws_size,
                              hipStream_t stream) {
    const float* x     = (const float*)d_in[0];
    const float* ew    = (const float*)d_in[1];
    const float* W1    = (const float*)d_in[2];
    const float* b1    = (const float*)d_in[3];
    const float* gamma = (const float*)d_in[4];
    const float* beta  = (const float*)d_in[5];
    const int*   src   = (const int*)d_in[6];
    const int*   dst   = (const int*)d_in[7];
    float* out = (float*)d_out;
    char*  ws  = (char*)d_ws;

    float* Z        = (float*)(ws + WS_Z);
    float* sums_x   = (float*)(ws + WS_SUMS_X);
    float* sumsq_x  = (float*)(ws + WS_SUMSQ_X);
    float* sum_avg  = (float*)(ws + WS_SUM_A);
    float* sumsq_avg= (float*)(ws + WS_SUMSQ_A);
    float* W1eff    = (float*)(ws + WS_W1EFF);
    float* b1eff    = (float*)(ws + WS_B1EFF);
    float* agg      = (float*)(ws + WS_AGG);

    hipMemsetAsync(ws, 0, WS_STATS_END, stream);
    hipMemsetAsync(agg, 0, (size_t)TT * NN * 64 * sizeof(float), stream);

    k_degree<<<(EE + 255) / 256, 256, 0, stream>>>(ew, dst, Z);
    k_rz<<<(NN + 255) / 256, 256, 0, stream>>>(Z);
    k_scatter<<<(EE * 64) / 256, 256, 0, stream>>>(x, ew, src, dst, agg);

    dim3 gs(1024, TT);
    k_stats_x<<<gs, 256, 0, stream>>>(x, sums_x, sumsq_x);
    k_stats_avg<<<gs, 256, 0, stream>>>(agg, Z, sum_avg, sumsq_avg);

    k_fold<<<1, 192, 0, stream>>>(W1, b1, gamma, beta, sums_x, sumsq_x,
                                  sum_avg, sumsq_avg, W1eff, b1eff);

    k_main<<<(TT * NN + 255) / 256, 256, 0, stream>>>(x, agg, Z, W1eff, b1eff, out);
}

// Round 2
// 694.016 us; speedup vs baseline: 2.0683x; 2.0683x over previous
//
#include <hip/hip_runtime.h>

#define TT 4
#define NN 50000
#define DH 64
#define EE 800000
#define BN_EPS 1e-5f
#define NB 196          // ceil(NN/256)

// ---------------- ws layout (byte offsets) ----------------
#define WS_Z        0          // 50000 f  -> 200000
#define WS_DEG      200704     // 50000 i  -> 400704   (memset [0,400704))
#define WS_CURSOR   400896     // 50000 i
#define WS_ROWSTART 601088     // 50001 i
#define WS_BSUM     801280     // 196 i
#define WS_BSCAN    802304     // 196 i
#define WS_SUMS_X   803328     // 256 f
#define WS_SUMSQ_X  804352     // 256 f
#define WS_SUM_A    805376     // 64 f
#define WS_SUMSQ_A  805632     // 64 f    (memset [803328,805888))
#define WS_W1EFF    806912     // 12288 f
#define WS_B1EFF    856064     // 64 f
#define WS_PACKED   860160     // 800000 int2 = 6.4 MB -> 7260160
#define WS_AVG      8388608    // 12.8M f = 51.2 MB -> ~59.6 MB total

__global__ void k_hist(const float* __restrict__ ew, const int* __restrict__ dst,
                       float* __restrict__ Z, int* __restrict__ deg) {
    int e = blockIdx.x * 256 + threadIdx.x;
    if (e < EE) {
        int d = dst[e];
        atomicAdd(&Z[d], ew[e]);
        atomicAdd(&deg[d], 1);
    }
}

__global__ void k_rz(float* __restrict__ Z) {
    int n = blockIdx.x * 256 + threadIdx.x;
    if (n < NN) {
        float z = Z[n];
        Z[n] = (z == 0.0f) ? 1.0f : (1.0f / z);
    }
}

__global__ void k_scan1(const int* __restrict__ deg, int* __restrict__ bsum) {
    __shared__ int ls[256];
    int i = blockIdx.x * 256 + threadIdx.x;
    ls[threadIdx.x] = (i < NN) ? deg[i] : 0;
    __syncthreads();
    for (int off = 128; off > 0; off >>= 1) {
        if (threadIdx.x < off) ls[threadIdx.x] += ls[threadIdx.x + off];
        __syncthreads();
    }
    if (threadIdx.x == 0) bsum[blockIdx.x] = ls[0];
}

__global__ void k_scan2(const int* __restrict__ bsum, int* __restrict__ bscan) {
    __shared__ int ls[256];
    int tid = threadIdx.x;
    int v = (tid < NB) ? bsum[tid] : 0;
    ls[tid] = v;
    __syncthreads();
    for (int off = 1; off < 256; off <<= 1) {
        int t = (tid >= off) ? ls[tid - off] : 0;
        __syncthreads();
        ls[tid] += t;
        __syncthreads();
    }
    if (tid < NB) bscan[tid] = ls[tid] - v;   // exclusive
}

__global__ void k_scan3(const int* __restrict__ deg, const int* __restrict__ bscan,
                        int* __restrict__ row_start, int* __restrict__ cursor) {
    __shared__ int ls[256];
    int i = blockIdx.x * 256 + threadIdx.x;
    int tid = threadIdx.x;
    int v = (i < NN) ? deg[i] : 0;
    ls[tid] = v;
    __syncthreads();
    for (int off = 1; off < 256; off <<= 1) {
        int t = (tid >= off) ? ls[tid - off] : 0;
        __syncthreads();
        ls[tid] += t;
        __syncthreads();
    }
    int s = ls[tid] - v + bscan[blockIdx.x];  // exclusive prefix
    if (i < NN) {
        row_start[i] = s;
        cursor[i] = s;
    }
    if (i == NN - 1) row_start[NN] = s + v;
}

__global__ void k_fill(const int* __restrict__ src, const int* __restrict__ dst,
                       const float* __restrict__ ew, int* __restrict__ cursor,
                       int2* __restrict__ packed) {
    int e = blockIdx.x * 256 + threadIdx.x;
    if (e < EE) {
        int d = dst[e];
        int p = atomicAdd(&cursor[d], 1);
        packed[p] = make_int2(src[e], __float_as_int(ew[e]));
    }
}

// one wave per node; lanes = 64 channels; gather-accumulate all 4 t's, write avg
__global__ __launch_bounds__(256) void k_agg(
    const float* __restrict__ x, const int2* __restrict__ packed,
    const int* __restrict__ row_start, const float* __restrict__ rZ,
    float* __restrict__ avg) {
    int n = blockIdx.x * 4 + (threadIdx.x >> 6);
    int c = threadIdx.x & 63;
    int rs = row_start[n], re = row_start[n + 1];
    float a0 = 0.f, a1 = 0.f, a2 = 0.f, a3 = 0.f;
    for (int e = rs; e < re; ++e) {
        int2 pk = packed[e];
        int s = pk.x;
        float w = __int_as_float(pk.y);
        const float* xp = x + (size_t)s * 64 + c;
        a0 = fmaf(w, xp[0 * NN * 64], a0);
        a1 = fmaf(w, xp[1 * NN * 64], a1);
        a2 = fmaf(w, xp[2 * NN * 64], a2);
        a3 = fmaf(w, xp[3 * NN * 64], a3);
    }
    float rz = rZ[n];
    size_t base = (size_t)n * 64 + c;
    avg[base + (size_t)0 * NN * 64] = a0 * rz;
    avg[base + (size_t)1 * NN * 64] = a1 * rz;
    avg[base + (size_t)2 * NN * 64] = a2 * rz;
    avg[base + (size_t)3 * NN * 64] = a3 * rz;
}

// per-(t,c) sum & sumsq of node_data
__global__ void k_stats_x(const float* __restrict__ x, float* __restrict__ sums,
                          float* __restrict__ sumsq) {
    int t = blockIdx.y;
    int g = blockIdx.x * 256 + threadIdx.x;
    int stride = gridDim.x * 256;               // multiple of 64 -> c fixed per thread
    const float* xt = x + (size_t)t * NN * 64;
    float s = 0.f, s2 = 0.f;
    for (int i = g; i < NN * 64; i += stride) {
        float v = xt[i];
        s += v; s2 += v * v;
    }
    __shared__ float ls[256], ls2[256];
    ls[threadIdx.x] = s; ls2[threadIdx.x] = s2;
    __syncthreads();
    if (threadIdx.x < 64) {
        s  = ls[threadIdx.x]  + ls[threadIdx.x + 64]  + ls[threadIdx.x + 128]  + ls[threadIdx.x + 192];
        s2 = ls2[threadIdx.x] + ls2[threadIdx.x + 64] + ls2[threadIdx.x + 128] + ls2[threadIdx.x + 192];
        atomicAdd(&sums[t * 64 + threadIdx.x], s);
        atomicAdd(&sumsq[t * 64 + threadIdx.x], s2);
    }
}

// per-c sum & sumsq of avg (already rZ-scaled), accumulated over all t
__global__ void k_stats_avg(const float* __restrict__ avg, float* __restrict__ sums,
                            float* __restrict__ sumsq) {
    int g = blockIdx.x * 256 + threadIdx.x;
    int stride = gridDim.x * 256;
    float s = 0.f, s2 = 0.f;
    for (size_t i = g; i < (size_t)TT * NN * 64; i += stride) {
        float v = avg[i];
        s += v; s2 += v * v;
    }
    __shared__ float ls[256], ls2[256];
    ls[threadIdx.x] = s; ls2[threadIdx.x] = s2;
    __syncthreads();
    if (threadIdx.x < 64) {
        s  = ls[threadIdx.x]  + ls[threadIdx.x + 64]  + ls[threadIdx.x + 128]  + ls[threadIdx.x + 192];
        s2 = ls2[threadIdx.x] + ls2[threadIdx.x + 64] + ls2[threadIdx.x + 128] + ls2[threadIdx.x + 192];
        atomicAdd(&sums[threadIdx.x], s);
        atomicAdd(&sumsq[threadIdx.x], s2);
    }
}

// finalize BN stats, fold gamma/beta/mu/rstd into W1eff / b1eff
__global__ void k_fold(const float* __restrict__ W1, const float* __restrict__ b1,
                       const float* __restrict__ gamma, const float* __restrict__ beta,
                       const float* __restrict__ sums_x, const float* __restrict__ sumsq_x,
                       const float* __restrict__ sum_avg, const float* __restrict__ sumsq_avg,
                       float* __restrict__ W1eff, float* __restrict__ b1eff) {
    __shared__ float gS[192], hS[192];
    int c = threadIdx.x;                        // 192 threads
    const float inv = 1.0f / (float)(TT * NN);
    if (c < 192) {
        float mu, ex2;
        if (c < 64) {
            float s = 0.f, s2 = 0.f;
            for (int t = 0; t < TT; ++t) { s += sums_x[t * 64 + c]; s2 += sumsq_x[t * 64 + c]; }
            mu = s * inv; ex2 = s2 * inv;
        } else if (c < 128) {
            int cc = c - 64;
            float s = 0.f, s2 = 0.f;
            for (int t = 0; t < TT - 1; ++t) { s += sums_x[t * 64 + cc]; s2 += sumsq_x[t * 64 + cc]; }
            mu = s * inv; ex2 = s2 * inv;       // t=0 prev row is zeros
        } else {
            int cc = c - 128;
            mu = sum_avg[cc] * inv; ex2 = sumsq_avg[cc] * inv;
        }
        float var = ex2 - mu * mu;
        float g = gamma[c] / sqrtf(var + BN_EPS);
        gS[c] = g;
        hS[c] = beta[c] - mu * g;
    }
    __syncthreads();
    for (int i = threadIdx.x; i < 64 * 192; i += blockDim.x) {
        int cc = i % 192;
        W1eff[i] = W1[i] * gS[cc];
    }
    if (threadIdx.x < 64) {
        int o = threadIdx.x;
        float acc = b1[o];
        for (int cc = 0; cc < 192; ++cc) acc += hS[cc] * W1[o * 192 + cc];
        b1eff[o] = acc;
    }
}

// main fused GEMM: one thread per row r=(t,n); 64 outputs in registers.
__global__ __launch_bounds__(256) void k_main(
    const float* __restrict__ x, const float* __restrict__ avg,
    const float* __restrict__ W, const float* __restrict__ bias,
    float* __restrict__ out) {
    int r = blockIdx.x * 256 + threadIdx.x;
    if (r >= TT * NN) return;
    int t = r / NN;
    float acc[64];
#pragma unroll
    for (int o = 0; o < 64; ++o) acc[o] = 0.f;

    const float* xrow = x + (size_t)r * 64;
    const float* prow = x + (size_t)(r - NN) * 64;  // only dereferenced when t>0
    const float* arow = avg + (size_t)r * 64;
    bool has_prev = (t > 0);

#pragma unroll 1
    for (int hc = 0; hc < 12; ++hc) {
        float a[16];
        int c0 = hc * 16;
        if (hc < 4) {
#pragma unroll
            for (int j = 0; j < 16; ++j) a[j] = xrow[c0 + j];
        } else if (hc < 8) {
            if (has_prev) {
#pragma unroll
                for (int j = 0; j < 16; ++j) a[j] = prow[c0 - 64 + j];
            } else {
#pragma unroll
                for (int j = 0; j < 16; ++j) a[j] = 0.f;
            }
        } else {
#pragma unroll
            for (int j = 0; j < 16; ++j) a[j] = arow[c0 - 128 + j];
        }
        const float* Wc = W + c0;                 // lane-uniform -> scalar loads
#pragma unroll
        for (int o = 0; o < 64; ++o) {
#pragma unroll
            for (int j = 0; j < 16; ++j) acc[o] = fmaf(a[j], Wc[o * 192 + j], acc[o]);
        }
    }
    float* orow = out + (size_t)r * 64;
#pragma unroll
    for (int o = 0; o < 64; ++o) orow[o] = fmaxf(acc[o] + bias[o], 0.f);
}

extern "C" void kernel_launch(void* const* d_in, const int* in_sizes, int n_in,
                              void* d_out, int out_size, void* d_ws, size_t ws_size,
                              hipStream_t stream) {
    const float* x     = (const float*)d_in[0];
    const float* ew    = (const float*)d_in[1];
    const float* W1    = (const float*)d_in[2];
    const float* b1    = (const float*)d_in[3];
    const float* gamma = (const float*)d_in[4];
    const float* beta  = (const float*)d_in[5];
    const int*   src   = (const int*)d_in[6];
    const int*   dst   = (const int*)d_in[7];
    float* out = (float*)d_out;
    char*  ws  = (char*)d_ws;

    float* Z        = (float*)(ws + WS_Z);
    int*   deg      = (int*)(ws + WS_DEG);
    int*   cursor   = (int*)(ws + WS_CURSOR);
    int*   row_start= (int*)(ws + WS_ROWSTART);
    int*   bsum     = (int*)(ws + WS_BSUM);
    int*   bscan    = (int*)(ws + WS_BSCAN);
    float* sums_x   = (float*)(ws + WS_SUMS_X);
    float* sumsq_x  = (float*)(ws + WS_SUMSQ_X);
    float* sum_avg  = (float*)(ws + WS_SUM_A);
    float* sumsq_avg= (float*)(ws + WS_SUMSQ_A);
    float* W1eff    = (float*)(ws + WS_W1EFF);
    float* b1eff    = (float*)(ws + WS_B1EFF);
    int2*  packed   = (int2*)(ws + WS_PACKED);
    float* avg      = (float*)(ws + WS_AVG);

    hipMemsetAsync(ws, 0, 400704, stream);                    // Z + deg
    hipMemsetAsync(ws + WS_SUMS_X, 0, 805888 - WS_SUMS_X, stream);  // stats

    k_hist<<<(EE + 255) / 256, 256, 0, stream>>>(ew, dst, Z, deg);
    k_rz<<<(NN + 255) / 256, 256, 0, stream>>>(Z);

    k_scan1<<<NB, 256, 0, stream>>>(deg, bsum);
    k_scan2<<<1, 256, 0, stream>>>(bsum, bscan);
    k_scan3<<<NB, 256, 0, stream>>>(deg, bscan, row_start, cursor);
    k_fill<<<(EE + 255) / 256, 256, 0, stream>>>(src, dst, ew, cursor, packed);

    k_agg<<<NN / 4, 256, 0, stream>>>(x, packed, row_start, Z, avg);

    dim3 gs(1024, TT);
    k_stats_x<<<gs, 256, 0, stream>>>(x, sums_x, sumsq_x);
    k_stats_avg<<<4096, 256, 0, stream>>>(avg, sum_avg, sumsq_avg);

    k_fold<<<1, 192, 0, stream>>>(W1, b1, gamma, beta, sums_x, sumsq_x,
                                  sum_avg, sumsq_avg, W1eff, b1eff);

    k_main<<<(TT * NN + 255) / 256, 256, 0, stream>>>(x, avg, W1eff, b1eff, out);
}

// Round 3
// 570.330 us; speedup vs baseline: 2.5169x; 1.2169x over previous
//
#include <hip/hip_runtime.h>

#define TT 4
#define NN 50000
#define DH 64
#define EE 800000
#define BN_EPS 1e-5f
#define NB 196          // ceil(NN/256)

typedef __attribute__((ext_vector_type(8))) short short8;
typedef __attribute__((ext_vector_type(4))) float floatx4;

// ---------------- ws layout (byte offsets) ----------------
#define WS_Z        0          // 50000 f
#define WS_DEG      200704     // 50000 i   (memset [0,400704))
#define WS_CURSOR   400896     // 50000 i
#define WS_ROWSTART 601088     // 50001 i
#define WS_BSUM     801280     // 196 i
#define WS_BSCAN    802304     // 196 i
#define WS_SUMS_X   803328     // 256 f
#define WS_SUMSQ_X  804352     // 256 f
#define WS_SUM_A    805376     // 64 f
#define WS_SUMSQ_A  805632     // 64 f    (memset [803328,805888))
#define WS_W1EFF    806912     // 12288 bf16 = 24576 B
#define WS_B1EFF    835584     // 64 f
#define WS_PACKED   860160     // 800000 int2 = 6.4 MB -> 7260160
#define WS_XB       8388608    // 200000*64 bf16 = 25.6 MB -> 33988608
#define WS_AVGB     34078720   // 200000*64 bf16 = 25.6 MB -> 59678720

__device__ __forceinline__ unsigned short f2b(float f) {
    unsigned int u = __float_as_uint(f);
    unsigned int r = (u + 0x7FFFu + ((u >> 16) & 1u)) >> 16;
    return (unsigned short)r;
}
__device__ __forceinline__ float b2f(unsigned short u) {
    return __uint_as_float((unsigned int)u << 16);
}

// x (fp32) -> xb (bf16), 2 elems per thread
__global__ void k_prep(const float* __restrict__ x, unsigned short* __restrict__ xb) {
    int i = blockIdx.x * 256 + threadIdx.x;      // covers 200000*32
    const float2* xp = (const float2*)x;
    float2 v = xp[i];
    unsigned int pk = (unsigned int)f2b(v.x) | ((unsigned int)f2b(v.y) << 16);
    ((unsigned int*)xb)[i] = pk;
}

__global__ void k_hist(const float* __restrict__ ew, const int* __restrict__ dst,
                       float* __restrict__ Z, int* __restrict__ deg) {
    int e = blockIdx.x * 256 + threadIdx.x;
    if (e < EE) {
        int d = dst[e];
        atomicAdd(&Z[d], ew[e]);
        atomicAdd(&deg[d], 1);
    }
}

__global__ void k_rz(float* __restrict__ Z) {
    int n = blockIdx.x * 256 + threadIdx.x;
    if (n < NN) {
        float z = Z[n];
        Z[n] = (z == 0.0f) ? 1.0f : (1.0f / z);
    }
}

__global__ void k_scan1(const int* __restrict__ deg, int* __restrict__ bsum) {
    __shared__ int ls[256];
    int i = blockIdx.x * 256 + threadIdx.x;
    ls[threadIdx.x] = (i < NN) ? deg[i] : 0;
    __syncthreads();
    for (int off = 128; off > 0; off >>= 1) {
        if (threadIdx.x < off) ls[threadIdx.x] += ls[threadIdx.x + off];
        __syncthreads();
    }
    if (threadIdx.x == 0) bsum[blockIdx.x] = ls[0];
}

__global__ void k_scan2(const int* __restrict__ bsum, int* __restrict__ bscan) {
    __shared__ int ls[256];
    int tid = threadIdx.x;
    int v = (tid < NB) ? bsum[tid] : 0;
    ls[tid] = v;
    __syncthreads();
    for (int off = 1; off < 256; off <<= 1) {
        int t = (tid >= off) ? ls[tid - off] : 0;
        __syncthreads();
        ls[tid] += t;
        __syncthreads();
    }
    if (tid < NB) bscan[tid] = ls[tid] - v;   // exclusive
}

__global__ void k_scan3(const int* __restrict__ deg, const int* __restrict__ bscan,
                        int* __restrict__ row_start, int* __restrict__ cursor) {
    __shared__ int ls[256];
    int i = blockIdx.x * 256 + threadIdx.x;
    int tid = threadIdx.x;
    int v = (i < NN) ? deg[i] : 0;
    ls[tid] = v;
    __syncthreads();
    for (int off = 1; off < 256; off <<= 1) {
        int t = (tid >= off) ? ls[tid - off] : 0;
        __syncthreads();
        ls[tid] += t;
        __syncthreads();
    }
    int s = ls[tid] - v + bscan[blockIdx.x];  // exclusive prefix
    if (i < NN) {
        row_start[i] = s;
        cursor[i] = s;
    }
    if (i == NN - 1) row_start[NN] = s + v;
}

__global__ void k_fill(const int* __restrict__ src, const int* __restrict__ dst,
                       const float* __restrict__ ew, int* __restrict__ cursor,
                       int2* __restrict__ packed) {
    int e = blockIdx.x * 256 + threadIdx.x;
    if (e < EE) {
        int d = dst[e];
        int p = atomicAdd(&cursor[d], 1);
        packed[p] = make_int2(src[e], __float_as_int(ew[e]));
    }
}

// one wave per node; lanes = 64 channels; gather bf16 x, write bf16 avg
__global__ __launch_bounds__(256) void k_agg(
    const unsigned short* __restrict__ xb, const int2* __restrict__ packed,
    const int* __restrict__ row_start, const float* __restrict__ rZ,
    unsigned short* __restrict__ avgb) {
    int n = blockIdx.x * 4 + (threadIdx.x >> 6);
    int c = threadIdx.x & 63;
    int rs = row_start[n], re = row_start[n + 1];
    float a0 = 0.f, a1 = 0.f, a2 = 0.f, a3 = 0.f;
    for (int e = rs; e < re; ++e) {
        int2 pk = packed[e];
        int s = pk.x;
        float w = __int_as_float(pk.y);
        const unsigned short* xp = xb + (size_t)s * 64 + c;
        a0 = fmaf(w, b2f(xp[0 * NN * 64]), a0);
        a1 = fmaf(w, b2f(xp[1 * NN * 64]), a1);
        a2 = fmaf(w, b2f(xp[2 * NN * 64]), a2);
        a3 = fmaf(w, b2f(xp[3 * NN * 64]), a3);
    }
    float rz = rZ[n];
    size_t base = (size_t)n * 64 + c;
    avgb[base + (size_t)0 * NN * 64] = f2b(a0 * rz);
    avgb[base + (size_t)1 * NN * 64] = f2b(a1 * rz);
    avgb[base + (size_t)2 * NN * 64] = f2b(a2 * rz);
    avgb[base + (size_t)3 * NN * 64] = f2b(a3 * rz);
}

// per-(t,c) sum & sumsq of node_data (fp32 x)
__global__ void k_stats_x(const float* __restrict__ x, float* __restrict__ sums,
                          float* __restrict__ sumsq) {
    int t = blockIdx.y;
    int g = blockIdx.x * 256 + threadIdx.x;
    int stride = gridDim.x * 256;               // multiple of 64 -> c fixed per thread
    const float* xt = x + (size_t)t * NN * 64;
    float s = 0.f, s2 = 0.f;
    for (int i = g; i < NN * 64; i += stride) {
        float v = xt[i];
        s += v; s2 += v * v;
    }
    __shared__ float ls[256], ls2[256];
    ls[threadIdx.x] = s; ls2[threadIdx.x] = s2;
    __syncthreads();
    if (threadIdx.x < 64) {
        s  = ls[threadIdx.x]  + ls[threadIdx.x + 64]  + ls[threadIdx.x + 128]  + ls[threadIdx.x + 192];
        s2 = ls2[threadIdx.x] + ls2[threadIdx.x + 64] + ls2[threadIdx.x + 128] + ls2[threadIdx.x + 192];
        atomicAdd(&sums[t * 64 + threadIdx.x], s);
        atomicAdd(&sumsq[t * 64 + threadIdx.x], s2);
    }
}

// per-c sum & sumsq of avg (bf16, already rZ-scaled)
__global__ void k_stats_avg(const unsigned short* __restrict__ avgb,
                            float* __restrict__ sums, float* __restrict__ sumsq) {
    int g = blockIdx.x * 256 + threadIdx.x;
    int stride = gridDim.x * 256;
    float s = 0.f, s2 = 0.f;
    for (size_t i = g; i < (size_t)TT * NN * 64; i += stride) {
        float v = b2f(avgb[i]);
        s += v; s2 += v * v;
    }
    __shared__ float ls[256], ls2[256];
    ls[threadIdx.x] = s; ls2[threadIdx.x] = s2;
    __syncthreads();
    if (threadIdx.x < 64) {
        s  = ls[threadIdx.x]  + ls[threadIdx.x + 64]  + ls[threadIdx.x + 128]  + ls[threadIdx.x + 192];
        s2 = ls2[threadIdx.x] + ls2[threadIdx.x + 64] + ls2[threadIdx.x + 128] + ls2[threadIdx.x + 192];
        atomicAdd(&sums[threadIdx.x], s);
        atomicAdd(&sumsq[threadIdx.x], s2);
    }
}

// finalize BN stats, fold gamma/beta/mu/rstd into bf16 W1eff / fp32 b1eff
__global__ void k_fold(const float* __restrict__ W1, const float* __restrict__ b1,
                       const float* __restrict__ gamma, const float* __restrict__ beta,
                       const float* __restrict__ sums_x, const float* __restrict__ sumsq_x,
                       const float* __restrict__ sum_avg, const float* __restrict__ sumsq_avg,
                       unsigned short* __restrict__ W1eff, float* __restrict__ b1eff) {
    __shared__ float gS[192], hS[192];
    int c = threadIdx.x;                        // 192 threads
    const float inv = 1.0f / (float)(TT * NN);
    if (c < 192) {
        float mu, ex2;
        if (c < 64) {
            float s = 0.f, s2 = 0.f;
            for (int t = 0; t < TT; ++t) { s += sums_x[t * 64 + c]; s2 += sumsq_x[t * 64 + c]; }
            mu = s * inv; ex2 = s2 * inv;
        } else if (c < 128) {
            int cc = c - 64;
            float s = 0.f, s2 = 0.f;
            for (int t = 0; t < TT - 1; ++t) { s += sums_x[t * 64 + cc]; s2 += sumsq_x[t * 64 + cc]; }
            mu = s * inv; ex2 = s2 * inv;       // t=0 prev row is zeros
        } else {
            int cc = c - 128;
            mu = sum_avg[cc] * inv; ex2 = sumsq_avg[cc] * inv;
        }
        float var = ex2 - mu * mu;
        float g = gamma[c] / sqrtf(var + BN_EPS);
        gS[c] = g;
        hS[c] = beta[c] - mu * g;
    }
    __syncthreads();
    for (int i = threadIdx.x; i < 64 * 192; i += blockDim.x) {
        int cc = i % 192;
        W1eff[i] = f2b(W1[i] * gS[cc]);
    }
    if (threadIdx.x < 64) {
        int o = threadIdx.x;
        float acc = b1[o];
        for (int cc = 0; cc < 192; ++cc) acc += hS[cc] * W1[o * 192 + cc];
        b1eff[o] = acc;
    }
}

// MFMA GEMM: block = 4 waves, wave = 16 rows x 64 outs (4 col-tiles), K=192
__global__ __launch_bounds__(256) void k_main(
    const unsigned short* __restrict__ xb, const unsigned short* __restrict__ avgb,
    const unsigned short* __restrict__ Wb, const float* __restrict__ bias,
    float* __restrict__ out) {
    int wave = threadIdx.x >> 6;
    int lane = threadIdx.x & 63;
    int r0 = blockIdx.x * 64 + wave * 16;
    int m = lane & 15;
    int q = lane >> 4;

    const unsigned short* xrow = xb   + (size_t)(r0 + m) * 64 + q * 8;
    const unsigned short* prow = xb   + (size_t)(r0 - NN + m) * 64 + q * 8;
    const unsigned short* arow = avgb + (size_t)(r0 + m) * 64 + q * 8;
    bool has_prev = (r0 >= NN);

    floatx4 acc[4];
#pragma unroll
    for (int ct = 0; ct < 4; ++ct) acc[ct] = (floatx4){0.f, 0.f, 0.f, 0.f};

    const short8 zf = (short8){0, 0, 0, 0, 0, 0, 0, 0};

#pragma unroll
    for (int kc = 0; kc < 6; ++kc) {
        short8 a;
        if (kc < 2) {
            a = *(const short8*)(xrow + kc * 32);
        } else if (kc < 4) {
            a = has_prev ? *(const short8*)(prow + (kc - 2) * 32) : zf;
        } else {
            a = *(const short8*)(arow + (kc - 4) * 32);
        }
#pragma unroll
        for (int ct = 0; ct < 4; ++ct) {
            short8 b = *(const short8*)(Wb + (size_t)(ct * 16 + m) * 192 + kc * 32 + q * 8);
            acc[ct] = __builtin_amdgcn_mfma_f32_16x16x32_bf16(a, b, acc[ct], 0, 0, 0);
        }
    }

#pragma unroll
    for (int ct = 0; ct < 4; ++ct) {
        float bv = bias[ct * 16 + m];
#pragma unroll
        for (int i = 0; i < 4; ++i) {
            int row = q * 4 + i;
            out[(size_t)(r0 + row) * 64 + ct * 16 + m] = fmaxf(acc[ct][i] + bv, 0.f);
        }
    }
}

extern "C" void kernel_launch(void* const* d_in, const int* in_sizes, int n_in,
                              void* d_out, int out_size, void* d_ws, size_t ws_size,
                              hipStream_t stream) {
    const float* x     = (const float*)d_in[0];
    const float* ew    = (const float*)d_in[1];
    const float* W1    = (const float*)d_in[2];
    const float* b1    = (const float*)d_in[3];
    const float* gamma = (const float*)d_in[4];
    const float* beta  = (const float*)d_in[5];
    const int*   src   = (const int*)d_in[6];
    const int*   dst   = (const int*)d_in[7];
    float* out = (float*)d_out;
    char*  ws  = (char*)d_ws;

    float* Z        = (float*)(ws + WS_Z);
    int*   deg      = (int*)(ws + WS_DEG);
    int*   cursor   = (int*)(ws + WS_CURSOR);
    int*   row_start= (int*)(ws + WS_ROWSTART);
    int*   bsum     = (int*)(ws + WS_BSUM);
    int*   bscan    = (int*)(ws + WS_BSCAN);
    float* sums_x   = (float*)(ws + WS_SUMS_X);
    float* sumsq_x  = (float*)(ws + WS_SUMSQ_X);
    float* sum_avg  = (float*)(ws + WS_SUM_A);
    float* sumsq_avg= (float*)(ws + WS_SUMSQ_A);
    unsigned short* W1eff = (unsigned short*)(ws + WS_W1EFF);
    float* b1eff    = (float*)(ws + WS_B1EFF);
    int2*  packed   = (int2*)(ws + WS_PACKED);
    unsigned short* xb   = (unsigned short*)(ws + WS_XB);
    unsigned short* avgb = (unsigned short*)(ws + WS_AVGB);

    hipMemsetAsync(ws, 0, 400704, stream);                          // Z + deg
    hipMemsetAsync(ws + WS_SUMS_X, 0, 805888 - WS_SUMS_X, stream);  // stats

    k_prep<<<(TT * NN * 32) / 256, 256, 0, stream>>>(x, xb);

    k_hist<<<(EE + 255) / 256, 256, 0, stream>>>(ew, dst, Z, deg);
    k_rz<<<(NN + 255) / 256, 256, 0, stream>>>(Z);

    k_scan1<<<NB, 256, 0, stream>>>(deg, bsum);
    k_scan2<<<1, 256, 0, stream>>>(bsum, bscan);
    k_scan3<<<NB, 256, 0, stream>>>(deg, bscan, row_start, cursor);
    k_fill<<<(EE + 255) / 256, 256, 0, stream>>>(src, dst, ew, cursor, packed);

    k_agg<<<NN / 4, 256, 0, stream>>>(xb, packed, row_start, Z, avgb);

    dim3 gs(1024, TT);
    k_stats_x<<<gs, 256, 0, stream>>>(x, sums_x, sumsq_x);
    k_stats_avg<<<4096, 256, 0, stream>>>(avgb, sum_avg, sumsq_avg);

    k_fold<<<1, 192, 0, stream>>>(W1, b1, gamma, beta, sums_x, sumsq_x,
                                  sum_avg, sumsq_avg, W1eff, b1eff);

    k_main<<<(TT * NN) / 64, 256, 0, stream>>>(xb, avgb, W1eff, b1eff, out);
}

// Round 4
// 424.944 us; speedup vs baseline: 3.3779x; 1.3421x over previous
//
#include <hip/hip_runtime.h>

#define TT 4
#define NN 50000
#define DH 64
#define EE 800000
#define BN_EPS 1e-5f
#define NB 196          // ceil(NN/256)
#define G1 64           // blocks per t for prep_stats
#define G2 128          // blocks for stats_avg

typedef __attribute__((ext_vector_type(8))) short short8;
typedef __attribute__((ext_vector_type(4))) float floatx4;

// ---------------- ws layout (byte offsets) ----------------
#define WS_Z        0          // 50000 f
#define WS_DEG      200704     // 50000 i   (memset [0,400704))
#define WS_CURSOR   400896     // 50000 i
#define WS_ROWSTART 601088     // 50001 i
#define WS_BSUM     801280     // 196 i
#define WS_BSCAN    802304     // 196 i
#define WS_PX       803328     // [4][G1][64] f = 65536 B
#define WS_PX2      868864     // 65536 B
#define WS_PA       934400     // [G2][64] f = 32768 B
#define WS_PA2      967168     // 32768 B
#define WS_W1EFF    999936     // 12288 bf16 = 24576 B
#define WS_B1EFF    1024512    // 64 f
#define WS_PACKED   1048576    // 800000 int2 = 6.4 MB
#define WS_XB       8388608    // 200000*64 bf16 = 25.6 MB
#define WS_AVGB     34078720   // 200000*64 bf16 = 25.6 MB -> ends 59678720

__device__ __forceinline__ unsigned short f2b(float f) {
    unsigned int u = __float_as_uint(f);
    unsigned int r = (u + 0x7FFFu + ((u >> 16) & 1u)) >> 16;
    return (unsigned short)r;
}
__device__ __forceinline__ float b2f(unsigned short u) {
    return __uint_as_float((unsigned int)u << 16);
}

// fused: x(fp32) -> xb(bf16) conversion + per-(t,c) sum/sumsq partials (no atomics)
__global__ __launch_bounds__(256) void k_prep_stats(
    const float* __restrict__ x, unsigned short* __restrict__ xb,
    float* __restrict__ PX, float* __restrict__ PX2) {
    int t = blockIdx.y;
    int tid = threadIdx.x;
    int g = blockIdx.x * 256 + tid;
    const float4* xt = (const float4*)(x + (size_t)t * NN * 64);
    unsigned short* xbt = xb + (size_t)t * NN * 64;
    float s[4] = {0.f, 0.f, 0.f, 0.f}, s2[4] = {0.f, 0.f, 0.f, 0.f};
    for (int v = g; v < NN * 16; v += G1 * 256) {     // stride mult of 16 -> c-group fixed
        float4 d = xt[v];
        ushort4 o;
        o.x = f2b(d.x); o.y = f2b(d.y); o.z = f2b(d.z); o.w = f2b(d.w);
        *(ushort4*)(xbt + (size_t)v * 4) = o;
        s[0] += d.x; s2[0] += d.x * d.x;
        s[1] += d.y; s2[1] += d.y * d.y;
        s[2] += d.z; s2[2] += d.z * d.z;
        s[3] += d.w; s2[3] += d.w * d.w;
    }
    __shared__ float ls[256 * 4], ls2[256 * 4];
#pragma unroll
    for (int j = 0; j < 4; ++j) { ls[tid * 4 + j] = s[j]; ls2[tid * 4 + j] = s2[j]; }
    __syncthreads();
    if (tid < 64) {
        int g16 = tid >> 2, comp = tid & 3;           // channel c=tid held by threads j: j&15==g16
        float rs = 0.f, rs2 = 0.f;
#pragma unroll
        for (int k = 0; k < 16; ++k) {
            int j = g16 + 16 * k;
            rs += ls[j * 4 + comp]; rs2 += ls2[j * 4 + comp];
        }
        int slot = (t * G1 + blockIdx.x) * 64 + tid;
        PX[slot] = rs; PX2[slot] = rs2;
    }
}

__global__ void k_hist(const float* __restrict__ ew, const int* __restrict__ dst,
                       float* __restrict__ Z, int* __restrict__ deg) {
    int e = blockIdx.x * 256 + threadIdx.x;
    if (e < EE) {
        int d = dst[e];
        atomicAdd(&Z[d], ew[e]);
        atomicAdd(&deg[d], 1);
    }
}

__global__ void k_rz(float* __restrict__ Z) {
    int n = blockIdx.x * 256 + threadIdx.x;
    if (n < NN) {
        float z = Z[n];
        Z[n] = (z == 0.0f) ? 1.0f : (1.0f / z);
    }
}

__global__ void k_scan1(const int* __restrict__ deg, int* __restrict__ bsum) {
    __shared__ int ls[256];
    int i = blockIdx.x * 256 + threadIdx.x;
    ls[threadIdx.x] = (i < NN) ? deg[i] : 0;
    __syncthreads();
    for (int off = 128; off > 0; off >>= 1) {
        if (threadIdx.x < off) ls[threadIdx.x] += ls[threadIdx.x + off];
        __syncthreads();
    }
    if (threadIdx.x == 0) bsum[blockIdx.x] = ls[0];
}

__global__ void k_scan2(const int* __restrict__ bsum, int* __restrict__ bscan) {
    __shared__ int ls[256];
    int tid = threadIdx.x;
    int v = (tid < NB) ? bsum[tid] : 0;
    ls[tid] = v;
    __syncthreads();
    for (int off = 1; off < 256; off <<= 1) {
        int t = (tid >= off) ? ls[tid - off] : 0;
        __syncthreads();
        ls[tid] += t;
        __syncthreads();
    }
    if (tid < NB) bscan[tid] = ls[tid] - v;   // exclusive
}

__global__ void k_scan3(const int* __restrict__ deg, const int* __restrict__ bscan,
                        int* __restrict__ row_start, int* __restrict__ cursor) {
    __shared__ int ls[256];
    int i = blockIdx.x * 256 + threadIdx.x;
    int tid = threadIdx.x;
    int v = (i < NN) ? deg[i] : 0;
    ls[tid] = v;
    __syncthreads();
    for (int off = 1; off < 256; off <<= 1) {
        int t = (tid >= off) ? ls[tid - off] : 0;
        __syncthreads();
        ls[tid] += t;
        __syncthreads();
    }
    int s = ls[tid] - v + bscan[blockIdx.x];  // exclusive prefix
    if (i < NN) {
        row_start[i] = s;
        cursor[i] = s;
    }
    if (i == NN - 1) row_start[NN] = s + v;
}

__global__ void k_fill(const int* __restrict__ src, const int* __restrict__ dst,
                       const float* __restrict__ ew, int* __restrict__ cursor,
                       int2* __restrict__ packed) {
    int e = blockIdx.x * 256 + threadIdx.x;
    if (e < EE) {
        int d = dst[e];
        int p = atomicAdd(&cursor[d], 1);
        packed[p] = make_int2(src[e], __float_as_int(ew[e]));
    }
}

// one wave per node; lane l -> (t = l>>4, channels 4*(l&15)..+3), ushort4 gathers
__global__ __launch_bounds__(256) void k_agg(
    const unsigned short* __restrict__ xb, const int2* __restrict__ packed,
    const int* __restrict__ row_start, const float* __restrict__ rZ,
    unsigned short* __restrict__ avgb) {
    int n = blockIdx.x * 4 + (threadIdx.x >> 6);
    int l = threadIdx.x & 63;
    int t = l >> 4;
    int cg = (l & 15) * 4;
    const unsigned short* xt = xb + (size_t)t * NN * 64 + cg;
    int rs = row_start[n], re = row_start[n + 1];
    float a0 = 0.f, a1 = 0.f, a2 = 0.f, a3 = 0.f;
    int e = rs;
    for (; e + 2 <= re; e += 2) {
        int2 p0 = packed[e], p1 = packed[e + 1];
        float w0 = __int_as_float(p0.y), w1 = __int_as_float(p1.y);
        ushort4 v0 = *(const ushort4*)(xt + (size_t)p0.x * 64);
        ushort4 v1 = *(const ushort4*)(xt + (size_t)p1.x * 64);
        a0 = fmaf(w0, b2f(v0.x), a0); a1 = fmaf(w0, b2f(v0.y), a1);
        a2 = fmaf(w0, b2f(v0.z), a2); a3 = fmaf(w0, b2f(v0.w), a3);
        a0 = fmaf(w1, b2f(v1.x), a0); a1 = fmaf(w1, b2f(v1.y), a1);
        a2 = fmaf(w1, b2f(v1.z), a2); a3 = fmaf(w1, b2f(v1.w), a3);
    }
    if (e < re) {
        int2 p0 = packed[e];
        float w0 = __int_as_float(p0.y);
        ushort4 v0 = *(const ushort4*)(xt + (size_t)p0.x * 64);
        a0 = fmaf(w0, b2f(v0.x), a0); a1 = fmaf(w0, b2f(v0.y), a1);
        a2 = fmaf(w0, b2f(v0.z), a2); a3 = fmaf(w0, b2f(v0.w), a3);
    }
    float rz = rZ[n];
    ushort4 o;
    o.x = f2b(a0 * rz); o.y = f2b(a1 * rz); o.z = f2b(a2 * rz); o.w = f2b(a3 * rz);
    *(ushort4*)(avgb + (size_t)t * NN * 64 + (size_t)n * 64 + cg) = o;
}

// per-c sum/sumsq partials of avg (bf16), short8 loads, no atomics
__global__ __launch_bounds__(256) void k_stats_avg(
    const unsigned short* __restrict__ avgb, float* __restrict__ PA,
    float* __restrict__ PA2) {
    int tid = threadIdx.x;
    int g = blockIdx.x * 256 + tid;
    const short8* av = (const short8*)avgb;
    float s[8], s2[8];
#pragma unroll
    for (int j = 0; j < 8; ++j) { s[j] = 0.f; s2[j] = 0.f; }
    for (int v = g; v < TT * NN * 8; v += G2 * 256) {  // stride mult of 8 -> c-group fixed
        short8 d = av[v];
#pragma unroll
        for (int j = 0; j < 8; ++j) {
            float f = b2f((unsigned short)d[j]);
            s[j] += f; s2[j] += f * f;
        }
    }
    __shared__ float ls[256 * 8], ls2[256 * 8];
#pragma unroll
    for (int j = 0; j < 8; ++j) { ls[tid * 8 + j] = s[j]; ls2[tid * 8 + j] = s2[j]; }
    __syncthreads();
    if (tid < 64) {
        int g8 = tid >> 3, comp = tid & 7;             // channel c=tid held by threads j: j&7==g8
        float rs = 0.f, rs2 = 0.f;
#pragma unroll
        for (int k = 0; k < 32; ++k) {
            int j = g8 + 8 * k;
            rs += ls[j * 8 + comp]; rs2 += ls2[j * 8 + comp];
        }
        PA[blockIdx.x * 64 + tid] = rs;
        PA2[blockIdx.x * 64 + tid] = rs2;
    }
}

// stage-2 reduce + BN fold into bf16 W1eff / fp32 b1eff
__global__ void k_fold(const float* __restrict__ W1, const float* __restrict__ b1,
                       const float* __restrict__ gamma, const float* __restrict__ beta,
                       const float* __restrict__ PX, const float* __restrict__ PX2,
                       const float* __restrict__ PA, const float* __restrict__ PA2,
                       unsigned short* __restrict__ W1eff, float* __restrict__ b1eff) {
    __shared__ float gS[192], hS[192];
    int c = threadIdx.x;                        // 192 threads
    const float inv = 1.0f / (float)(TT * NN);
    if (c < 192) {
        float s = 0.f, s2 = 0.f;
        if (c < 64) {
            for (int i = 0; i < TT * G1; ++i) { s += PX[i * 64 + c]; s2 += PX2[i * 64 + c]; }
        } else if (c < 128) {
            int cc = c - 64;                    // prev: t=0..2 only (t=0 row of prev is zeros)
            for (int i = 0; i < (TT - 1) * G1; ++i) { s += PX[i * 64 + cc]; s2 += PX2[i * 64 + cc]; }
        } else {
            int cc = c - 128;
            for (int i = 0; i < G2; ++i) { s += PA[i * 64 + cc]; s2 += PA2[i * 64 + cc]; }
        }
        float mu = s * inv, ex2 = s2 * inv;
        float var = ex2 - mu * mu;
        float g = gamma[c] / sqrtf(var + BN_EPS);
        gS[c] = g;
        hS[c] = beta[c] - mu * g;
    }
    __syncthreads();
    for (int i = threadIdx.x; i < 64 * 192; i += blockDim.x) {
        int cc = i % 192;
        W1eff[i] = f2b(W1[i] * gS[cc]);
    }
    if (threadIdx.x < 64) {
        int o = threadIdx.x;
        float acc = b1[o];
        for (int cc = 0; cc < 192; ++cc) acc += hS[cc] * W1[o * 192 + cc];
        b1eff[o] = acc;
    }
}

// MFMA GEMM: block = 4 waves, wave = 16 rows x 64 outs (4 col-tiles), K=192
__global__ __launch_bounds__(256) void k_main(
    const unsigned short* __restrict__ xb, const unsigned short* __restrict__ avgb,
    const unsigned short* __restrict__ Wb, const float* __restrict__ bias,
    float* __restrict__ out) {
    int wave = threadIdx.x >> 6;
    int lane = threadIdx.x & 63;
    int r0 = blockIdx.x * 64 + wave * 16;
    int m = lane & 15;
    int q = lane >> 4;

    const unsigned short* xrow = xb   + (size_t)(r0 + m) * 64 + q * 8;
    const unsigned short* prow = xb   + (size_t)(r0 - NN + m) * 64 + q * 8;
    const unsigned short* arow = avgb + (size_t)(r0 + m) * 64 + q * 8;
    bool has_prev = (r0 >= NN);

    floatx4 acc[4];
#pragma unroll
    for (int ct = 0; ct < 4; ++ct) acc[ct] = (floatx4){0.f, 0.f, 0.f, 0.f};

    const short8 zf = (short8){0, 0, 0, 0, 0, 0, 0, 0};

#pragma unroll
    for (int kc = 0; kc < 6; ++kc) {
        short8 a;
        if (kc < 2) {
            a = *(const short8*)(xrow + kc * 32);
        } else if (kc < 4) {
            a = has_prev ? *(const short8*)(prow + (kc - 2) * 32) : zf;
        } else {
            a = *(const short8*)(arow + (kc - 4) * 32);
        }
#pragma unroll
        for (int ct = 0; ct < 4; ++ct) {
            short8 b = *(const short8*)(Wb + (size_t)(ct * 16 + m) * 192 + kc * 32 + q * 8);
            acc[ct] = __builtin_amdgcn_mfma_f32_16x16x32_bf16(a, b, acc[ct], 0, 0, 0);
        }
    }

#pragma unroll
    for (int ct = 0; ct < 4; ++ct) {
        float bv = bias[ct * 16 + m];
#pragma unroll
        for (int i = 0; i < 4; ++i) {
            int row = q * 4 + i;
            out[(size_t)(r0 + row) * 64 + ct * 16 + m] = fmaxf(acc[ct][i] + bv, 0.f);
        }
    }
}

extern "C" void kernel_launch(void* const* d_in, const int* in_sizes, int n_in,
                              void* d_out, int out_size, void* d_ws, size_t ws_size,
                              hipStream_t stream) {
    const float* x     = (const float*)d_in[0];
    const float* ew    = (const float*)d_in[1];
    const float* W1    = (const float*)d_in[2];
    const float* b1    = (const float*)d_in[3];
    const float* gamma = (const float*)d_in[4];
    const float* beta  = (const float*)d_in[5];
    const int*   src   = (const int*)d_in[6];
    const int*   dst   = (const int*)d_in[7];
    float* out = (float*)d_out;
    char*  ws  = (char*)d_ws;

    float* Z        = (float*)(ws + WS_Z);
    int*   deg      = (int*)(ws + WS_DEG);
    int*   cursor   = (int*)(ws + WS_CURSOR);
    int*   row_start= (int*)(ws + WS_ROWSTART);
    int*   bsum     = (int*)(ws + WS_BSUM);
    int*   bscan    = (int*)(ws + WS_BSCAN);
    float* PX       = (float*)(ws + WS_PX);
    float* PX2      = (float*)(ws + WS_PX2);
    float* PA       = (float*)(ws + WS_PA);
    float* PA2      = (float*)(ws + WS_PA2);
    unsigned short* W1eff = (unsigned short*)(ws + WS_W1EFF);
    float* b1eff    = (float*)(ws + WS_B1EFF);
    int2*  packed   = (int2*)(ws + WS_PACKED);
    unsigned short* xb   = (unsigned short*)(ws + WS_XB);
    unsigned short* avgb = (unsigned short*)(ws + WS_AVGB);

    hipMemsetAsync(ws, 0, 400704, stream);          // Z + deg only

    k_prep_stats<<<dim3(G1, TT), 256, 0, stream>>>(x, xb, PX, PX2);

    k_hist<<<(EE + 255) / 256, 256, 0, stream>>>(ew, dst, Z, deg);
    k_rz<<<(NN + 255) / 256, 256, 0, stream>>>(Z);

    k_scan1<<<NB, 256, 0, stream>>>(deg, bsum);
    k_scan2<<<1, 256, 0, stream>>>(bsum, bscan);
    k_scan3<<<NB, 256, 0, stream>>>(deg, bscan, row_start, cursor);
    k_fill<<<(EE + 255) / 256, 256, 0, stream>>>(src, dst, ew, cursor, packed);

    k_agg<<<NN / 4, 256, 0, stream>>>(xb, packed, row_start, Z, avgb);

    k_stats_avg<<<G2, 256, 0, stream>>>(avgb, PA, PA2);

    k_fold<<<1, 192, 0, stream>>>(W1, b1, gamma, beta, PX, PX2, PA, PA2, W1eff, b1eff);

    k_main<<<(TT * NN) / 64, 256, 0, stream>>>(xb, avgb, W1eff, b1eff, out);
}

// Round 5
// 358.846 us; speedup vs baseline: 4.0002x; 1.1842x over previous
//
#include <hip/hip_runtime.h>

#define TT 4
#define NN 50000
#define DH 64
#define EE 800000
#define BN_EPS 1e-5f
#define NB 196          // ceil(NN/256)
#define G1 64           // blocks per t for prep_stats
#define G2 128          // blocks for stats_avg

typedef __attribute__((ext_vector_type(8))) short short8;
typedef __attribute__((ext_vector_type(4))) float floatx4;

// ---------------- ws layout (byte offsets) ----------------
#define WS_DEG      0          // 50000 i   (memset [0,200000))
#define WS_ROWSTART 200704     // 50001 i
#define WS_BSUM     401408     // 196 i
#define WS_BSCAN    402432     // 196 i
#define WS_PX       403456     // [4][G1][64] f = 65536 B
#define WS_PX2      468992     // 65536 B
#define WS_PA       534528     // [G2][64] f = 32768 B
#define WS_PA2      567296     // 32768 B
#define WS_W1EFF    600064     // 12288 bf16 = 24576 B
#define WS_B1EFF    624640     // 64 f
#define WS_PACKED   1048576    // 800000 int2 = 6.4 MB -> 7448576
#define WS_XB       8388608    // 200000*64 bf16 = 25.6 MB -> 33988608
#define WS_AVGB     34078720   // 200000*64 bf16 = 25.6 MB -> ends 59678720
#define WS_RANK     34078720   // 800000 i (aliases avgb region; dead before k_agg)

__device__ __forceinline__ unsigned short f2b(float f) {
    unsigned int u = __float_as_uint(f);
    unsigned int r = (u + 0x7FFFu + ((u >> 16) & 1u)) >> 16;
    return (unsigned short)r;
}
__device__ __forceinline__ float b2f(unsigned short u) {
    return __uint_as_float((unsigned int)u << 16);
}

// fused: x(fp32) -> xb(bf16) conversion + per-(t,c) sum/sumsq partials (no atomics)
__global__ __launch_bounds__(256) void k_prep_stats(
    const float* __restrict__ x, unsigned short* __restrict__ xb,
    float* __restrict__ PX, float* __restrict__ PX2) {
    int t = blockIdx.y;
    int tid = threadIdx.x;
    int g = blockIdx.x * 256 + tid;
    const float4* xt = (const float4*)(x + (size_t)t * NN * 64);
    unsigned short* xbt = xb + (size_t)t * NN * 64;
    float s[4] = {0.f, 0.f, 0.f, 0.f}, s2[4] = {0.f, 0.f, 0.f, 0.f};
    for (int v = g; v < NN * 16; v += G1 * 256) {     // stride mult of 16 -> c-group fixed
        float4 d = xt[v];
        ushort4 o;
        o.x = f2b(d.x); o.y = f2b(d.y); o.z = f2b(d.z); o.w = f2b(d.w);
        *(ushort4*)(xbt + (size_t)v * 4) = o;
        s[0] += d.x; s2[0] += d.x * d.x;
        s[1] += d.y; s2[1] += d.y * d.y;
        s[2] += d.z; s2[2] += d.z * d.z;
        s[3] += d.w; s2[3] += d.w * d.w;
    }
    __shared__ float ls[256 * 4], ls2[256 * 4];
#pragma unroll
    for (int j = 0; j < 4; ++j) { ls[tid * 4 + j] = s[j]; ls2[tid * 4 + j] = s2[j]; }
    __syncthreads();
    if (tid < 64) {
        int g16 = tid >> 2, comp = tid & 3;           // channel c=tid held by threads j: j&15==g16
        float rs = 0.f, rs2 = 0.f;
#pragma unroll
        for (int k = 0; k < 16; ++k) {
            int j = g16 + 16 * k;
            rs += ls[j * 4 + comp]; rs2 += ls2[j * 4 + comp];
        }
        int slot = (t * G1 + blockIdx.x) * 64 + tid;
        PX[slot] = rs; PX2[slot] = rs2;
    }
}

// single atomic stream: per-edge rank within its dst bucket + deg histogram
__global__ void k_rank(const int* __restrict__ dst, int* __restrict__ deg,
                       int* __restrict__ rank) {
    int e = blockIdx.x * 256 + threadIdx.x;
    if (e < EE) rank[e] = atomicAdd(&deg[dst[e]], 1);
}

__global__ void k_scan1(const int* __restrict__ deg, int* __restrict__ bsum) {
    __shared__ int ls[256];
    int i = blockIdx.x * 256 + threadIdx.x;
    ls[threadIdx.x] = (i < NN) ? deg[i] : 0;
    __syncthreads();
    for (int off = 128; off > 0; off >>= 1) {
        if (threadIdx.x < off) ls[threadIdx.x] += ls[threadIdx.x + off];
        __syncthreads();
    }
    if (threadIdx.x == 0) bsum[blockIdx.x] = ls[0];
}

__global__ void k_scan2(const int* __restrict__ bsum, int* __restrict__ bscan) {
    __shared__ int ls[256];
    int tid = threadIdx.x;
    int v = (tid < NB) ? bsum[tid] : 0;
    ls[tid] = v;
    __syncthreads();
    for (int off = 1; off < 256; off <<= 1) {
        int t = (tid >= off) ? ls[tid - off] : 0;
        __syncthreads();
        ls[tid] += t;
        __syncthreads();
    }
    if (tid < NB) bscan[tid] = ls[tid] - v;   // exclusive
}

__global__ void k_scan3(const int* __restrict__ deg, const int* __restrict__ bscan,
                        int* __restrict__ row_start) {
    __shared__ int ls[256];
    int i = blockIdx.x * 256 + threadIdx.x;
    int tid = threadIdx.x;
    int v = (i < NN) ? deg[i] : 0;
    ls[tid] = v;
    __syncthreads();
    for (int off = 1; off < 256; off <<= 1) {
        int t = (tid >= off) ? ls[tid - off] : 0;
        __syncthreads();
        ls[tid] += t;
        __syncthreads();
    }
    int s = ls[tid] - v + bscan[blockIdx.x];  // exclusive prefix
    if (i < NN) row_start[i] = s;
    if (i == NN - 1) row_start[NN] = s + v;
}

// atomic-free CSR fill: position = row_start[dst] + rank
__global__ void k_fill2(const int* __restrict__ src, const int* __restrict__ dst,
                        const float* __restrict__ ew, const int* __restrict__ rank,
                        const int* __restrict__ row_start, int2* __restrict__ packed) {
    int e = blockIdx.x * 256 + threadIdx.x;
    if (e < EE) {
        int p = row_start[dst[e]] + rank[e];
        packed[p] = make_int2(src[e], __float_as_int(ew[e]));
    }
}

// one wave per node; lane l -> (t = l>>4, channels 4*(l&15)..+3), ushort4 gathers.
// Z (= sum of edge weights) computed inline per lane — identical across lanes.
__global__ __launch_bounds__(256) void k_agg(
    const unsigned short* __restrict__ xb, const int2* __restrict__ packed,
    const int* __restrict__ row_start, unsigned short* __restrict__ avgb) {
    int n = blockIdx.x * 4 + (threadIdx.x >> 6);
    int l = threadIdx.x & 63;
    int t = l >> 4;
    int cg = (l & 15) * 4;
    const unsigned short* xt = xb + (size_t)t * NN * 64 + cg;
    int rs = row_start[n], re = row_start[n + 1];
    float a0 = 0.f, a1 = 0.f, a2 = 0.f, a3 = 0.f, wsum = 0.f;
    int e = rs;
    for (; e + 2 <= re; e += 2) {
        int2 p0 = packed[e], p1 = packed[e + 1];
        float w0 = __int_as_float(p0.y), w1 = __int_as_float(p1.y);
        ushort4 v0 = *(const ushort4*)(xt + (size_t)p0.x * 64);
        ushort4 v1 = *(const ushort4*)(xt + (size_t)p1.x * 64);
        wsum += w0 + w1;
        a0 = fmaf(w0, b2f(v0.x), a0); a1 = fmaf(w0, b2f(v0.y), a1);
        a2 = fmaf(w0, b2f(v0.z), a2); a3 = fmaf(w0, b2f(v0.w), a3);
        a0 = fmaf(w1, b2f(v1.x), a0); a1 = fmaf(w1, b2f(v1.y), a1);
        a2 = fmaf(w1, b2f(v1.z), a2); a3 = fmaf(w1, b2f(v1.w), a3);
    }
    if (e < re) {
        int2 p0 = packed[e];
        float w0 = __int_as_float(p0.y);
        ushort4 v0 = *(const ushort4*)(xt + (size_t)p0.x * 64);
        wsum += w0;
        a0 = fmaf(w0, b2f(v0.x), a0); a1 = fmaf(w0, b2f(v0.y), a1);
        a2 = fmaf(w0, b2f(v0.z), a2); a3 = fmaf(w0, b2f(v0.w), a3);
    }
    float rz = (wsum == 0.f) ? 1.f : (1.f / wsum);
    ushort4 o;
    o.x = f2b(a0 * rz); o.y = f2b(a1 * rz); o.z = f2b(a2 * rz); o.w = f2b(a3 * rz);
    *(ushort4*)(avgb + (size_t)t * NN * 64 + (size_t)n * 64 + cg) = o;
}

// per-c sum/sumsq partials of avg (bf16), short8 loads, no atomics
__global__ __launch_bounds__(256) void k_stats_avg(
    const unsigned short* __restrict__ avgb, float* __restrict__ PA,
    float* __restrict__ PA2) {
    int tid = threadIdx.x;
    int g = blockIdx.x * 256 + tid;
    const short8* av = (const short8*)avgb;
    float s[8], s2[8];
#pragma unroll
    for (int j = 0; j < 8; ++j) { s[j] = 0.f; s2[j] = 0.f; }
    for (int v = g; v < TT * NN * 8; v += G2 * 256) {  // stride mult of 8 -> c-group fixed
        short8 d = av[v];
#pragma unroll
        for (int j = 0; j < 8; ++j) {
            float f = b2f((unsigned short)d[j]);
            s[j] += f; s2[j] += f * f;
        }
    }
    __shared__ float ls[256 * 8], ls2[256 * 8];
#pragma unroll
    for (int j = 0; j < 8; ++j) { ls[tid * 8 + j] = s[j]; ls2[tid * 8 + j] = s2[j]; }
    __syncthreads();
    if (tid < 64) {
        int g8 = tid >> 3, comp = tid & 7;             // channel c=tid held by threads j: j&7==g8
        float rs = 0.f, rs2 = 0.f;
#pragma unroll
        for (int k = 0; k < 32; ++k) {
            int j = g8 + 8 * k;
            rs += ls[j * 8 + comp]; rs2 += ls2[j * 8 + comp];
        }
        PA[blockIdx.x * 64 + tid] = rs;
        PA2[blockIdx.x * 64 + tid] = rs2;
    }
}

// stage-2 reduce + BN fold into bf16 W1eff / fp32 b1eff
__global__ void k_fold(const float* __restrict__ W1, const float* __restrict__ b1,
                       const float* __restrict__ gamma, const float* __restrict__ beta,
                       const float* __restrict__ PX, const float* __restrict__ PX2,
                       const float* __restrict__ PA, const float* __restrict__ PA2,
                       unsigned short* __restrict__ W1eff, float* __restrict__ b1eff) {
    __shared__ float gS[192], hS[192];
    int c = threadIdx.x;                        // 192 threads
    const float inv = 1.0f / (float)(TT * NN);
    if (c < 192) {
        float s = 0.f, s2 = 0.f;
        if (c < 64) {
            for (int i = 0; i < TT * G1; ++i) { s += PX[i * 64 + c]; s2 += PX2[i * 64 + c]; }
        } else if (c < 128) {
            int cc = c - 64;                    // prev: t=0..2 only (t=0 row of prev is zeros)
            for (int i = 0; i < (TT - 1) * G1; ++i) { s += PX[i * 64 + cc]; s2 += PX2[i * 64 + cc]; }
        } else {
            int cc = c - 128;
            for (int i = 0; i < G2; ++i) { s += PA[i * 64 + cc]; s2 += PA2[i * 64 + cc]; }
        }
        float mu = s * inv, ex2 = s2 * inv;
        float var = ex2 - mu * mu;
        float g = gamma[c] / sqrtf(var + BN_EPS);
        gS[c] = g;
        hS[c] = beta[c] - mu * g;
    }
    __syncthreads();
    for (int i = threadIdx.x; i < 64 * 192; i += blockDim.x) {
        int cc = i % 192;
        W1eff[i] = f2b(W1[i] * gS[cc]);
    }
    if (threadIdx.x < 64) {
        int o = threadIdx.x;
        float acc = b1[o];
        for (int cc = 0; cc < 192; ++cc) acc += hS[cc] * W1[o * 192 + cc];
        b1eff[o] = acc;
    }
}

// MFMA GEMM: block = 4 waves, wave = 16 rows x 64 outs (4 col-tiles), K=192
__global__ __launch_bounds__(256) void k_main(
    const unsigned short* __restrict__ xb, const unsigned short* __restrict__ avgb,
    const unsigned short* __restrict__ Wb, const float* __restrict__ bias,
    float* __restrict__ out) {
    int wave = threadIdx.x >> 6;
    int lane = threadIdx.x & 63;
    int r0 = blockIdx.x * 64 + wave * 16;
    int m = lane & 15;
    int q = lane >> 4;

    const unsigned short* xrow = xb   + (size_t)(r0 + m) * 64 + q * 8;
    const unsigned short* prow = xb   + (size_t)(r0 - NN + m) * 64 + q * 8;
    const unsigned short* arow = avgb + (size_t)(r0 + m) * 64 + q * 8;
    bool has_prev = (r0 >= NN);

    floatx4 acc[4];
#pragma unroll
    for (int ct = 0; ct < 4; ++ct) acc[ct] = (floatx4){0.f, 0.f, 0.f, 0.f};

    const short8 zf = (short8){0, 0, 0, 0, 0, 0, 0, 0};

#pragma unroll
    for (int kc = 0; kc < 6; ++kc) {
        short8 a;
        if (kc < 2) {
            a = *(const short8*)(xrow + kc * 32);
        } else if (kc < 4) {
            a = has_prev ? *(const short8*)(prow + (kc - 2) * 32) : zf;
        } else {
            a = *(const short8*)(arow + (kc - 4) * 32);
        }
#pragma unroll
        for (int ct = 0; ct < 4; ++ct) {
            short8 b = *(const short8*)(Wb + (size_t)(ct * 16 + m) * 192 + kc * 32 + q * 8);
            acc[ct] = __builtin_amdgcn_mfma_f32_16x16x32_bf16(a, b, acc[ct], 0, 0, 0);
        }
    }

#pragma unroll
    for (int ct = 0; ct < 4; ++ct) {
        float bv = bias[ct * 16 + m];
#pragma unroll
        for (int i = 0; i < 4; ++i) {
            int row = q * 4 + i;
            out[(size_t)(r0 + row) * 64 + ct * 16 + m] = fmaxf(acc[ct][i] + bv, 0.f);
        }
    }
}

extern "C" void kernel_launch(void* const* d_in, const int* in_sizes, int n_in,
                              void* d_out, int out_size, void* d_ws, size_t ws_size,
                              hipStream_t stream) {
    const float* x     = (const float*)d_in[0];
    const float* ew    = (const float*)d_in[1];
    const float* W1    = (const float*)d_in[2];
    const float* b1    = (const float*)d_in[3];
    const float* gamma = (const float*)d_in[4];
    const float* beta  = (const float*)d_in[5];
    const int*   src   = (const int*)d_in[6];
    const int*   dst   = (const int*)d_in[7];
    float* out = (float*)d_out;
    char*  ws  = (char*)d_ws;

    int*   deg      = (int*)(ws + WS_DEG);
    int*   row_start= (int*)(ws + WS_ROWSTART);
    int*   bsum     = (int*)(ws + WS_BSUM);
    int*   bscan    = (int*)(ws + WS_BSCAN);
    float* PX       = (float*)(ws + WS_PX);
    float* PX2      = (float*)(ws + WS_PX2);
    float* PA       = (float*)(ws + WS_PA);
    float* PA2      = (float*)(ws + WS_PA2);
    unsigned short* W1eff = (unsigned short*)(ws + WS_W1EFF);
    float* b1eff    = (float*)(ws + WS_B1EFF);
    int2*  packed   = (int2*)(ws + WS_PACKED);
    unsigned short* xb   = (unsigned short*)(ws + WS_XB);
    unsigned short* avgb = (unsigned short*)(ws + WS_AVGB);
    int*   rank     = (int*)(ws + WS_RANK);

    hipMemsetAsync(ws, 0, 200000, stream);          // deg only

    k_prep_stats<<<dim3(G1, TT), 256, 0, stream>>>(x, xb, PX, PX2);

    k_rank<<<(EE + 255) / 256, 256, 0, stream>>>(dst, deg, rank);

    k_scan1<<<NB, 256, 0, stream>>>(deg, bsum);
    k_scan2<<<1, 256, 0, stream>>>(bsum, bscan);
    k_scan3<<<NB, 256, 0, stream>>>(deg, bscan, row_start);
    k_fill2<<<(EE + 255) / 256, 256, 0, stream>>>(src, dst, ew, rank, row_start, packed);

    k_agg<<<NN / 4, 256, 0, stream>>>(xb, packed, row_start, avgb);

    k_stats_avg<<<G2, 256, 0, stream>>>(avgb, PA, PA2);

    k_fold<<<1, 192, 0, stream>>>(W1, b1, gamma, beta, PX, PX2, PA, PA2, W1eff, b1eff);

    k_main<<<(TT * NN) / 64, 256, 0, stream>>>(xb, avgb, W1eff, b1eff, out);
}